// Round 5
// baseline (678.761 us; speedup 1.0000x reference)
//
#include <hip/hip_runtime.h>
#include <hip/hip_bf16.h>
#include <math.h>

#define B_ROWS 8192
#define DIN    1024
#define DH     1024
#define HD     256
#define DP     1365
#define DP2    2730
#define NUP    2816   // padded N for up GEMM (11 * 256)
#define KDN    1408   // padded K for down GEMM (44 * 32)

typedef __bf16 bf16x8 __attribute__((ext_vector_type(8)));
typedef float  f32x4  __attribute__((ext_vector_type(4)));
typedef unsigned short ushort_t;

__device__ __forceinline__ unsigned short f2bf(float f) {
    union { __hip_bfloat16 b; unsigned short u; } v; v.b = __float2bfloat16(f); return v.u;
}
__device__ __forceinline__ float bf2f(unsigned short u) {
    union { __hip_bfloat16 b; unsigned short u; } v; v.u = u; return __bfloat162float(v.b);
}

// ---------------------------------------------------------------- prep: h_prev -> bf16
__global__ __launch_bounds__(256) void prep_hprev(const float* __restrict__ hp,
                                                  ushort_t* __restrict__ out) {
    size_t i = ((size_t)blockIdx.x * 256 + threadIdx.x) * 8;
    float4 a = *(const float4*)(hp + i);
    float4 b = *(const float4*)(hp + i + 4);
    union { unsigned short s[8]; uint4 v; } o;
    o.s[0] = f2bf(a.x); o.s[1] = f2bf(a.y); o.s[2] = f2bf(a.z); o.s[3] = f2bf(a.w);
    o.s[4] = f2bf(b.x); o.s[5] = f2bf(b.y); o.s[6] = f2bf(b.z); o.s[7] = f2bf(b.w);
    *(uint4*)(out + i) = o.v;
}

// ------------------------------- prep: gate weights -> WT[g][n][k] bf16, K=1280 (W | R-block)
__global__ __launch_bounds__(256) void prep_wgates(
    const float* __restrict__ Wz, const float* __restrict__ Wi,
    const float* __restrict__ Wf, const float* __restrict__ Wo,
    const float* __restrict__ Rz, const float* __restrict__ Ri,
    const float* __restrict__ Rf, const float* __restrict__ Ro,
    ushort_t* __restrict__ WT) {
    int g = blockIdx.z;
    const float* W = (g == 0) ? Wz : (g == 1) ? Wi : (g == 2) ? Wf : Wo;
    const float* R = (g == 0) ? Rz : (g == 1) ? Ri : (g == 2) ? Rf : Ro;
    int n  = blockIdx.x * 256 + threadIdx.x;
    int k0 = blockIdx.y * 8;
    union { unsigned short s[8]; uint4 v; } o;
    if (k0 < 1024) {
        #pragma unroll
        for (int j = 0; j < 8; ++j) o.s[j] = f2bf(W[(size_t)(k0 + j) * DH + n]);
    } else {
        int h = n >> 8, e = n & 255, d0 = k0 - 1024;
        #pragma unroll
        for (int j = 0; j < 8; ++j) o.s[j] = f2bf(R[h * 65536 + (d0 + j) * 256 + e]);
    }
    *(uint4*)(WT + (size_t)g * 1024 * 1280 + (size_t)n * 1280 + k0) = o.v;
}

// ------------------------------- prep: Wup -> WupT[n][k] bf16 (n padded to 2816, pad rows = 0)
__global__ __launch_bounds__(256) void prep_wup(const float* __restrict__ Wup,
                                                ushort_t* __restrict__ WupT) {
    int n  = blockIdx.x * 256 + threadIdx.x;   // < 2816
    int k0 = blockIdx.y * 8;
    union { unsigned short s[8]; uint4 v; } o;
    #pragma unroll
    for (int j = 0; j < 8; ++j)
        o.s[j] = (n < DP2) ? f2bf(Wup[(size_t)(k0 + j) * DP2 + n]) : (unsigned short)0;
    *(uint4*)(WupT + (size_t)n * 1024 + k0) = o.v;
}

// ------------------------------- prep: Wdown -> WdnT[n][k] bf16 (k padded to 1408, pad = 0)
__global__ __launch_bounds__(256) void prep_wdown(const float* __restrict__ Wdown,
                                                  ushort_t* __restrict__ WdnT) {
    int n  = blockIdx.x * 256 + threadIdx.x;   // < 1024
    int k0 = blockIdx.y * 8;
    union { unsigned short s[8]; uint4 v; } o;
    #pragma unroll
    for (int j = 0; j < 8; ++j) {
        int k = k0 + j;
        o.s[j] = (k < DP) ? f2bf(Wdown[(size_t)k * DIN + n]) : (unsigned short)0;
    }
    *(uint4*)(WdnT + (size_t)n * KDN + k0) = o.v;
}

// ---------------------------------------------------------------- LayerNorm -> bf16
__global__ __launch_bounds__(256) void ln_kernel(const float* __restrict__ x,
                                                 const float* __restrict__ w,
                                                 const float* __restrict__ b,
                                                 ushort_t* __restrict__ xn) {
    int row = blockIdx.x;
    int tid = threadIdx.x;
    const float4 v = *(const float4*)(x + (size_t)row * DIN + tid * 4);
    float s  = v.x + v.y + v.z + v.w;
    float sq = v.x*v.x + v.y*v.y + v.z*v.z + v.w*v.w;
    #pragma unroll
    for (int off = 32; off; off >>= 1) {
        s  += __shfl_xor(s, off);
        sq += __shfl_xor(sq, off);
    }
    __shared__ float ss[8];
    int wid = tid >> 6, lane = tid & 63;
    if (lane == 0) { ss[wid] = s; ss[4 + wid] = sq; }
    __syncthreads();
    s  = ss[0] + ss[1] + ss[2] + ss[3];
    sq = ss[4] + ss[5] + ss[6] + ss[7];
    float mu  = s * (1.0f / DIN);
    float var = sq * (1.0f / DIN) - mu * mu;
    float inv = rsqrtf(var + 1e-5f);
    int c = tid * 4;
    float4 wv = *(const float4*)(w + c);
    float4 bv = *(const float4*)(b + c);
    union { unsigned short s4[4]; uint2 v2; } o;
    o.s4[0] = f2bf((v.x - mu) * inv * wv.x + bv.x);
    o.s4[1] = f2bf((v.y - mu) * inv * wv.y + bv.y);
    o.s4[2] = f2bf((v.z - mu) * inv * wv.z + bv.z);
    o.s4[3] = f2bf((v.w - mu) * inv * wv.w + bv.w);
    *(uint2*)(xn + (size_t)row * DIN + c) = o.v2;
}

// ================================================================ 256x256 GEMM core
// 512 threads, 8 waves (2 wm x 4 wn), per-wave tile 128x64, BK=32, dbuf, reg-staged.
// LDS chunked layout: addr(row,k8) = (row>>4)*1024 + k8*256 + (row&15)*16  (bytes)
// -> every ds_write_b128 / ds_read_b128 is wave-contiguous (conflict-minimal).
template<int NK, int SW>
__device__ __forceinline__ void gemm_core256(
    const ushort_t* __restrict__ aP0, const ushort_t* __restrict__ aP1, int lda,
    const ushort_t* __restrict__ bP, int ldb,
    char* AshB, char* BshB, f32x4 (&acc)[8][4])
{
    int tid = threadIdx.x, lane = tid & 63, wave = tid >> 6;
    int wm = wave >> 2, wn = wave & 3;
    int trow = tid >> 1, koff = (tid & 1) * 16;
    int l15 = lane & 15, l4 = lane >> 4;
    int wA  = ((trow >> 4) << 10) + ((tid & 1) << 9) + ((trow & 15) << 4);
    int raA = (wm << 13) + (l4 << 8) + (l15 << 4);
    int raB = (wn << 12) + (l4 << 8) + (l15 << 4);
    const ushort_t* aRow0 = aP0 + (size_t)trow * lda + koff;
    const ushort_t* aRow1 = aP1 + (size_t)trow * lda + koff;
    const ushort_t* bRow  = bP  + (size_t)trow * ldb + koff;

    auto loadAB = [&](int kt, bf16x8& a0, bf16x8& a1, bf16x8& b0, bf16x8& b1) {
        const ushort_t* p = (SW >= NK || kt < SW) ? aRow0 + kt * 32
                                                  : aRow1 + (kt - SW) * 32;
        a0 = *(const bf16x8*)p;
        a1 = *(const bf16x8*)(p + 8);
        const ushort_t* q = bRow + kt * 32;
        b0 = *(const bf16x8*)q;
        b1 = *(const bf16x8*)(q + 8);
    };
    auto stage = [&](char* A, char* B_, bf16x8 a0, bf16x8 a1, bf16x8 b0, bf16x8 b1) {
        *(bf16x8*)(A + wA)        = a0;
        *(bf16x8*)(A + wA + 256)  = a1;
        *(bf16x8*)(B_ + wA)       = b0;
        *(bf16x8*)(B_ + wA + 256) = b1;
    };
    auto compute = [&](const char* A, const char* B_) {
        bf16x8 af[8], bv[4];
        #pragma unroll
        for (int i = 0; i < 8; ++i) af[i] = *(const bf16x8*)(A + raA + i * 1024);
        #pragma unroll
        for (int i = 0; i < 4; ++i) bv[i] = *(const bf16x8*)(B_ + raB + i * 1024);
        #pragma unroll
        for (int mi = 0; mi < 8; ++mi)
            #pragma unroll
            for (int ni = 0; ni < 4; ++ni)
                acc[mi][ni] = __builtin_amdgcn_mfma_f32_16x16x32_bf16(af[mi], bv[ni], acc[mi][ni], 0, 0, 0);
    };

    {
        bf16x8 a0, a1, b0, b1;
        loadAB(0, a0, a1, b0, b1);
        stage(AshB, BshB, a0, a1, b0, b1);
    }
    __syncthreads();
    for (int kt = 0; kt < NK; kt += 2) {
        bf16x8 a0, a1, b0, b1;
        loadAB(kt + 1, a0, a1, b0, b1);         // issue early; latency under MFMA
        compute(AshB, BshB);
        stage(AshB + 16384, BshB + 16384, a0, a1, b0, b1);
        __syncthreads();
        if (kt + 2 < NK) loadAB(kt + 2, a0, a1, b0, b1);
        compute(AshB + 16384, BshB + 16384);
        if (kt + 2 < NK) {
            stage(AshB, BshB, a0, a1, b0, b1);
            __syncthreads();
        }
    }
}

// ---------------------------------------------------------------- gates GEMM
__global__ __launch_bounds__(512, 2) void gemm_gates_bf(
    const ushort_t* __restrict__ xn, const ushort_t* __restrict__ hp,
    const ushort_t* __restrict__ WT,
    const float* __restrict__ bz, const float* __restrict__ bi,
    const float* __restrict__ bf_, const float* __restrict__ bo,
    const float* __restrict__ rbz, const float* __restrict__ rbi,
    const float* __restrict__ rbf, const float* __restrict__ rbo,
    ushort_t* __restrict__ gates) {
    // grid 4 x 32 x 4 = 512 blocks; bijective XCD swizzle
    int bid = blockIdx.x + (blockIdx.y << 2) + (blockIdx.z << 7);
    int wgs = (bid & 7) * 64 + (bid >> 3);
    int bxi = wgs & 3, rest = wgs >> 2, byi = rest & 31, g = rest >> 5;
    const float* bias = (g == 0) ? bz  : (g == 1) ? bi  : (g == 2) ? bf_ : bo;
    const float* rb   = (g == 0) ? rbz : (g == 1) ? rbi : (g == 2) ? rbf : rbo;
    const ushort_t* Wg = WT + (size_t)g * 1024 * 1280;
    int m0 = byi * 256, n0 = bxi * 256, head = bxi;

    __shared__ __align__(16) char Ash[2][16384];
    __shared__ __align__(16) char Bsh[2][16384];
    f32x4 acc[8][4];
    #pragma unroll
    for (int i = 0; i < 8; ++i)
        #pragma unroll
        for (int j = 0; j < 4; ++j) acc[i][j] = (f32x4){0.f, 0.f, 0.f, 0.f};

    gemm_core256<40, 32>(xn + (size_t)m0 * 1024,
                         hp + (size_t)m0 * 1024 + head * 256, 1024,
                         Wg + (size_t)n0 * 1280, 1280,
                         &Ash[0][0], &Bsh[0][0], acc);

    int lane = threadIdx.x & 63, wave = threadIdx.x >> 6;
    int wm = wave >> 2, wn = wave & 3;
    int l15 = lane & 15, l4 = lane >> 4;
    ushort_t* og = gates + (size_t)g * B_ROWS * DH;
    #pragma unroll
    for (int ni = 0; ni < 4; ++ni) {
        int col = n0 + wn * 64 + ni * 16 + l15;
        float badd = bias[col] + rb[col];
        #pragma unroll
        for (int mi = 0; mi < 8; ++mi) {
            int rbase = m0 + wm * 128 + mi * 16 + l4 * 4;
            #pragma unroll
            for (int j = 0; j < 4; ++j)
                og[(size_t)(rbase + j) * DH + col] = f2bf(acc[mi][ni][j] + badd);
        }
    }
}

// ---------------------------------------------------------------- pointwise sLSTM + GroupNorm
__global__ __launch_bounds__(256) void pointwise_gn(
    const ushort_t* __restrict__ gbf,
    const float* __restrict__ c_prev, const float* __restrict__ n_prev,
    const float* __restrict__ m_prev, const float* __restrict__ gn_w,
    const float* __restrict__ gn_b, float* __restrict__ out,
    ushort_t* __restrict__ htn) {
    int row = blockIdx.x;
    int tid = threadIdx.x;
    int head = tid >> 6, lane = tid & 63;
    int col = head * HD + lane * 4;
    size_t idx = (size_t)row * DH + col;
    const size_t N = (size_t)B_ROWS * DH;

    float zv[4], ivv[4], fv[4], ov[4];
    {
        union { uint2 v; unsigned short s[4]; } t;
        t.v = *(const uint2*)(gbf + idx);
        for (int j = 0; j < 4; ++j) zv[j] = bf2f(t.s[j]);
        t.v = *(const uint2*)(gbf + N + idx);
        for (int j = 0; j < 4; ++j) ivv[j] = bf2f(t.s[j]);
        t.v = *(const uint2*)(gbf + 2 * N + idx);
        for (int j = 0; j < 4; ++j) fv[j] = bf2f(t.s[j]);
        t.v = *(const uint2*)(gbf + 3 * N + idx);
        for (int j = 0; j < 4; ++j) ov[j] = bf2f(t.s[j]);
    }
    float4 cp = *(const float4*)(c_prev + idx);
    float4 np = *(const float4*)(n_prev + idx);
    float4 mp = *(const float4*)(m_prev + idx);
    float cpv[4] = {cp.x, cp.y, cp.z, cp.w};
    float npv[4] = {np.x, np.y, np.z, np.w};
    float mpv[4] = {mp.x, mp.y, mp.z, mp.w};

    float htv[4], ctv[4], ntv[4], mtv[4];
    float s = 0.f, sq = 0.f;
    #pragma unroll
    for (int j = 0; j < 4; ++j) {
        float zt = tanhf(zv[j]);
        float ot = 1.0f / (1.0f + expf(-ov[j]));
        float mt = fmaxf(fv[j] + mpv[j], ivv[j]);
        float it = expf(ivv[j] - mt);
        float ft = expf(fv[j] + mpv[j] - mt);
        float ct = ft * cpv[j] + it * zt;
        float nt = ft * npv[j] + it;
        float h  = ot * (ct / (nt + 1e-13f));
        htv[j] = h; ctv[j] = ct; ntv[j] = nt; mtv[j] = mt;
        s += h; sq += h * h;
    }
    *(float4*)(out + N     + idx) = make_float4(htv[0], htv[1], htv[2], htv[3]);
    *(float4*)(out + 2 * N + idx) = make_float4(ctv[0], ctv[1], ctv[2], ctv[3]);
    *(float4*)(out + 3 * N + idx) = make_float4(ntv[0], ntv[1], ntv[2], ntv[3]);
    *(float4*)(out + 4 * N + idx) = make_float4(mtv[0], mtv[1], mtv[2], mtv[3]);

    #pragma unroll
    for (int off = 1; off < 64; off <<= 1) {
        s  += __shfl_xor(s, off);
        sq += __shfl_xor(sq, off);
    }
    float mean = s * (1.0f / HD);
    float var  = fmaxf(sq * (1.0f / HD) - mean * mean, 0.0f);
    float inv  = rsqrtf(var + 1e-5f);
    float4 gw = *(const float4*)(gn_w + col);
    float4 gb = *(const float4*)(gn_b + col);
    float gwv[4] = {gw.x, gw.y, gw.z, gw.w};
    float gbv[4] = {gb.x, gb.y, gb.z, gb.w};
    union { unsigned short s4[4]; uint2 v2; } o;
    #pragma unroll
    for (int j = 0; j < 4; ++j)
        o.s4[j] = f2bf((htv[j] - mean) * inv * gwv[j] + gbv[j]);
    *(uint2*)(htn + idx) = o.v2;
}

// ---------------------------------------------------------------- up GEMM
__global__ __launch_bounds__(512, 2) void gemm_up_bf(const ushort_t* __restrict__ htn,
                                                     const ushort_t* __restrict__ WupT,
                                                     const float* __restrict__ bup,
                                                     ushort_t* __restrict__ up) {
    // grid 11 x 32 = 352 blocks; 352 = 8*44 bijective swizzle
    int bid = blockIdx.x + blockIdx.y * 11;
    int wgs = (bid & 7) * 44 + (bid >> 3);
    int bxi = wgs % 11, byi = wgs / 11;
    int m0 = byi * 256, n0 = bxi * 256;

    __shared__ __align__(16) char Ash[2][16384];
    __shared__ __align__(16) char Bsh[2][16384];
    f32x4 acc[8][4];
    #pragma unroll
    for (int i = 0; i < 8; ++i)
        #pragma unroll
        for (int j = 0; j < 4; ++j) acc[i][j] = (f32x4){0.f, 0.f, 0.f, 0.f};

    const ushort_t* aP = htn + (size_t)m0 * 1024;
    gemm_core256<32, 32>(aP, aP, 1024, WupT + (size_t)n0 * 1024, 1024,
                         &Ash[0][0], &Bsh[0][0], acc);

    int lane = threadIdx.x & 63, wave = threadIdx.x >> 6;
    int wm = wave >> 2, wn = wave & 3;
    int l15 = lane & 15, l4 = lane >> 4;
    #pragma unroll
    for (int ni = 0; ni < 4; ++ni) {
        int col = n0 + wn * 64 + ni * 16 + l15;
        float badd = (col < DP2) ? bup[col] : 0.f;
        #pragma unroll
        for (int mi = 0; mi < 8; ++mi) {
            int rbase = m0 + wm * 128 + mi * 16 + l4 * 4;
            #pragma unroll
            for (int j = 0; j < 4; ++j)
                up[(size_t)(rbase + j) * NUP + col] = f2bf(acc[mi][ni][j] + badd);
        }
    }
}

// ---------------------------------------------------------------- GEGLU -> act bf16 (K-padded)
__global__ __launch_bounds__(256) void gelu_kernel(const ushort_t* __restrict__ up,
                                                   ushort_t* __restrict__ act) {
    int row = blockIdx.y;
    int c = blockIdx.x * 256 + threadIdx.x;
    if (c >= KDN) return;
    float v = 0.f;
    if (c < DP) {
        float s = bf2f(up[(size_t)row * NUP + c]);
        float g = bf2f(up[(size_t)row * NUP + DP + c]);
        v = s * 0.5f * g * (1.0f + erff(g * 0.70710678118654752f));
    }
    act[(size_t)row * KDN + c] = f2bf(v);  // zero-pads cols [1365,1408)
}

// ---------------------------------------------------------------- down GEMM + residual (fp32 out)
__global__ __launch_bounds__(512, 2) void gemm_down_bf(const ushort_t* __restrict__ act,
                                                       const ushort_t* __restrict__ WdnT,
                                                       const float* __restrict__ bdown,
                                                       const float* __restrict__ x,
                                                       float* __restrict__ y) {
    // grid 4 x 32 = 128 blocks; bijective swizzle
    int bid = blockIdx.x + (blockIdx.y << 2);
    int wgs = (bid & 7) * 16 + (bid >> 3);
    int bxi = wgs & 3, byi = wgs >> 2;
    int m0 = byi * 256, n0 = bxi * 256;

    __shared__ __align__(16) char Ash[2][16384];
    __shared__ __align__(16) char Bsh[2][16384];
    f32x4 acc[8][4];
    #pragma unroll
    for (int i = 0; i < 8; ++i)
        #pragma unroll
        for (int j = 0; j < 4; ++j) acc[i][j] = (f32x4){0.f, 0.f, 0.f, 0.f};

    const ushort_t* aP = act + (size_t)m0 * KDN;
    gemm_core256<44, 44>(aP, aP, KDN, WdnT + (size_t)n0 * KDN, KDN,
                         &Ash[0][0], &Bsh[0][0], acc);

    int lane = threadIdx.x & 63, wave = threadIdx.x >> 6;
    int wm = wave >> 2, wn = wave & 3;
    int l15 = lane & 15, l4 = lane >> 4;
    #pragma unroll
    for (int ni = 0; ni < 4; ++ni) {
        int col = n0 + wn * 64 + ni * 16 + l15;
        float bd = bdown[col];
        #pragma unroll
        for (int mi = 0; mi < 8; ++mi) {
            int rbase = m0 + wm * 128 + mi * 16 + l4 * 4;
            #pragma unroll
            for (int j = 0; j < 4; ++j) {
                int r = rbase + j;
                y[(size_t)r * DIN + col] = acc[mi][ni][j] + bd + x[(size_t)r * DIN + col];
            }
        }
    }
}

// ---------------------------------------------------------------- launch
extern "C" void kernel_launch(void* const* d_in, const int* in_sizes, int n_in,
                              void* d_out, int out_size, void* d_ws, size_t ws_size,
                              hipStream_t stream) {
    (void)in_sizes; (void)n_in; (void)out_size; (void)ws_size;
    const float* x      = (const float*)d_in[0];
    const float* h_prev = (const float*)d_in[1];
    const float* c_prev = (const float*)d_in[2];
    const float* n_prev = (const float*)d_in[3];
    const float* m_prev = (const float*)d_in[4];
    const float* ln_w   = (const float*)d_in[5];
    const float* ln_b   = (const float*)d_in[6];
    const float* Wz = (const float*)d_in[7];  const float* bz = (const float*)d_in[8];
    const float* Wi = (const float*)d_in[9];  const float* bi = (const float*)d_in[10];
    const float* Wf = (const float*)d_in[11]; const float* bf_ = (const float*)d_in[12];
    const float* Wo = (const float*)d_in[13]; const float* bo = (const float*)d_in[14];
    const float* Rz = (const float*)d_in[15]; const float* rbz = (const float*)d_in[16];
    const float* Ri = (const float*)d_in[17]; const float* rbi = (const float*)d_in[18];
    const float* Rf = (const float*)d_in[19]; const float* rbf = (const float*)d_in[20];
    const float* Ro = (const float*)d_in[21]; const float* rbo = (const float*)d_in[22];
    const float* gn_w = (const float*)d_in[23]; const float* gn_b = (const float*)d_in[24];
    const float* Wup  = (const float*)d_in[25]; const float* bup  = (const float*)d_in[26];
    const float* Wdown = (const float*)d_in[27]; const float* bdown = (const float*)d_in[28];

    // ---- workspace carve (bytes, all 16B-aligned)
    char* w = (char*)d_ws;
    ushort_t* hp_bf  = (ushort_t*)(w);                       // 16,777,216
    ushort_t* WTg    = (ushort_t*)(w + 16777216);            // 10,485,760
    ushort_t* WupT   = (ushort_t*)(w + 27262976);            //  5,767,168
    ushort_t* WdnT   = (ushort_t*)(w + 33030144);            //  2,883,584
    ushort_t* xn_bf  = (ushort_t*)(w + 35913728);            // 16,777,216 (reused as htn)
    ushort_t* htn_bf = xn_bf;
    char*     big    = w + 52690944;
    ushort_t* gates_bf = (ushort_t*)big;                     // 67,108,864 (dead after pointwise)
    ushort_t* up_bf    = (ushort_t*)big;                     // 46,137,344
    ushort_t* act_bf   = (ushort_t*)(big + 46137344);        // 23,068,672
    float* out = (float*)d_out;  // [y, ht, ct, nt, mt]

    prep_hprev <<<4096, 256, 0, stream>>>(h_prev, hp_bf);
    prep_wgates<<<dim3(4, 160, 4), 256, 0, stream>>>(Wz, Wi, Wf, Wo, Rz, Ri, Rf, Ro, WTg);
    prep_wup   <<<dim3(11, 128), 256, 0, stream>>>(Wup, WupT);
    prep_wdown <<<dim3(4, 176), 256, 0, stream>>>(Wdown, WdnT);
    ln_kernel  <<<B_ROWS, 256, 0, stream>>>(x, ln_w, ln_b, xn_bf);

    gemm_gates_bf<<<dim3(4, 32, 4), 512, 0, stream>>>(
        xn_bf, hp_bf, WTg, bz, bi, bf_, bo, rbz, rbi, rbf, rbo, gates_bf);

    pointwise_gn<<<B_ROWS, 256, 0, stream>>>(
        gates_bf, c_prev, n_prev, m_prev, gn_w, gn_b, out, htn_bf);

    gemm_up_bf<<<dim3(11, 32), 512, 0, stream>>>(htn_bf, WupT, bup, up_bf);

    gelu_kernel<<<dim3(6, B_ROWS), 256, 0, stream>>>(up_bf, act_bf);

    gemm_down_bf<<<dim3(4, 32), 512, 0, stream>>>(act_bf, WdnT, bdown, x, out);
}